// Round 3
// baseline (111.852 us; speedup 1.0000x reference)
//
#include <hip/hip_runtime.h>

typedef _Float16 h8 __attribute__((ext_vector_type(8)));
typedef _Float16 h4 __attribute__((ext_vector_type(4)));
typedef float f4 __attribute__((ext_vector_type(4)));
typedef unsigned int uint32;

#define NT 7   // n-tiles: 112 output cols (100 + pad)
#define KC 4   // k-chunks of 32: 128 (100 + pad)

__global__ __launch_bounds__(256, 2)
void grnn_fused(const float* __restrict__ times,
                const float* __restrict__ Qw,
                const float* __restrict__ Qb,
                const float* __restrict__ Ww,
                const float* __restrict__ Wb,
                const float* __restrict__ Pw,
                const float* __restrict__ Pb,
                float* __restrict__ out)
{
  // Hs stride 132 halves: even-row b64 A-reads are 2-way (free) bank-wise.
  __shared__ __align__(16) _Float16 Hs[256][132];   // 67584 B (also Ww fp32 staging)
  __shared__ __align__(16) float t_s[1024];
  __shared__ __align__(16) float qw_s[128];
  __shared__ __align__(16) float qb_s[128];
  __shared__ __align__(16) float qbw_s[128];        // Qb + Wb

  const int tid  = threadIdx.x;
  const int wave = tid >> 6;
  const int lane = tid & 63;
  const int l15  = lane & 15;
  const int kg   = lane >> 4;
  const int tree = blockIdx.x;

  // ---- phase 0: stage times, Q vectors, and raw Ww (fp32) into Hs ----
  {
    const float* tg = times + tree * 1023;
    for (int i = tid; i < 1023; i += 256) t_s[i] = tg[i];
    if (tid < 128) {
      float qw = 0.f, qb = 0.f, wb = 0.f;
      if (tid < 100) { qw = Qw[tid]; qb = Qb[tid]; wb = Wb[tid]; }
      qw_s[tid] = qw; qb_s[tid] = qb; qbw_s[tid] = qb + wb;
    }
    f4* wsv = (f4*)&Hs[0][0];
    const f4* wg = (const f4*)Ww;            // 10000 floats = 2500 float4
    for (int i = tid; i < 2500; i += 256) wsv[i] = wg[i];
  }
  __syncthreads();

  // ---- phase 1: persistent W fragments (B[k][n] = Ww[n][k]) ----
  // Only ever indexed with unrolled compile-time constants -> must stay VGPR.
  h8 wf[NT][KC];
  {
    const float* wsf = (const float*)&Hs[0][0];
    #pragma unroll
    for (int nt = 0; nt < NT; ++nt) {
      const int r = nt * 16 + l15;           // output feature (Ww row)
      #pragma unroll
      for (int kc = 0; kc < KC; ++kc) {
        const int kb = kc * 32 + kg * 8;
        h8 v;
        #pragma unroll
        for (int j = 0; j < 8; ++j) v[j] = (_Float16)0.f;
        if (r < 100 && kb < 100) {
          const int lim = 100 - kb;          // 4 (kb==96) or >=8
          const int base = r * 100 + kb;
          #pragma unroll
          for (int j = 0; j < 8; ++j)
            if (j < lim) v[j] = (_Float16)wsf[base + j];
        }
        wf[nt][kc] = v;
      }
    }
  }
  __syncthreads();

// MFMA + epilogue for one m-tile: D row=(lane>>4)*4+reg, col=lane&15.
// Macro (not lambda/fn): no pointers to register arrays are ever formed.
#define DO_MT(MT, AFR, S) do {                                                \
    _Pragma("unroll")                                                         \
    for (int nt_ = 0; nt_ < NT; ++nt_) {                                      \
      f4 acc_ = {0.f, 0.f, 0.f, 0.f};                                         \
      _Pragma("unroll")                                                       \
      for (int kc_ = 0; kc_ < KC; ++kc_)                                      \
        acc_ = __builtin_amdgcn_mfma_f32_16x16x32_f16(AFR[kc_], wf[nt_][kc_], \
                                                      acc_, 0, 0, 0);         \
      const int o_ = nt_ * 16 + l15;                                          \
      if (o_ < 100) {                                                         \
        const float qw_ = qw_s[o_];                                           \
        const float qbw_ = qbw_s[o_];                                         \
        const int mr_ = (MT) * 16 + kg * 4;                                   \
        _Pragma("unroll")                                                     \
        for (int r_ = 0; r_ < 4; ++r_) {                                      \
          float tv_ = t_s[(S) + mr_ + r_];                                    \
          float v_ = acc_[r_] + tv_ * qw_ + qbw_;                             \
          Hs[mr_ + r_][o_] = (_Float16)fmaxf(v_, 0.f);                        \
        }                                                                     \
      }                                                                       \
    }                                                                         \
  } while (0)

// A fragment = comb[m][k] = Hs[2m][k] + Hs[2m+1][k], A[m=lane&15][k=kg*8+j]
#define LOAD_AFR(MT, AFR) do {                                                \
    const int m2_ = ((MT) * 16 + l15) * 2;                                    \
    _Pragma("unroll")                                                         \
    for (int kc_ = 0; kc_ < KC; ++kc_) {                                      \
      const int kb_ = kc_ * 32 + kg * 8;                                      \
      h4 a0_ = *(const h4*)&Hs[m2_][kb_];                                     \
      h4 b0_ = *(const h4*)&Hs[m2_][kb_ + 4];                                 \
      h4 a1_ = *(const h4*)&Hs[m2_ + 1][kb_];                                 \
      h4 b1_ = *(const h4*)&Hs[m2_ + 1][kb_ + 4];                             \
      h4 lo_ = a0_ + a1_, hi_ = b0_ + b1_;                                    \
      AFR[kc_] = __builtin_shufflevector(lo_, hi_, 0, 1, 2, 3, 4, 5, 6, 7);   \
    }                                                                         \
  } while (0)

  // ---- phase 2: zero pad cols 100..131, then level 8 with fused leaves ----
  {
    uint32* hw = (uint32*)&Hs[0][0];
    for (int i = tid; i < 256 * 16; i += 256) {
      const int row = i >> 4;
      hw[row * 66 + 50 + (i & 15)] = 0u;
    }
  }
  {
    #pragma unroll
    for (int i = 0; i < 4; ++i) {
      const int mt = wave + 4 * i;         // 16 m-tiles over 4 waves
      const int m = mt * 16 + l15;
      const float t0 = t_s[511 + 2 * m];   // leaf children of level-8 node m
      const float t1 = t_s[512 + 2 * m];
      h8 af[KC];
      #pragma unroll
      for (int kc = 0; kc < KC; ++kc) {
        const int kb = kc * 32 + kg * 8;
        const f4 qwa = *(const f4*)&qw_s[kb];
        const f4 qwb = *(const f4*)&qw_s[kb + 4];
        const f4 qba = *(const f4*)&qb_s[kb];
        const f4 qbb = *(const f4*)&qb_s[kb + 4];
        #pragma unroll
        for (int j = 0; j < 4; ++j) {
          float h0 = fmaxf(t0 * qwa[j] + qba[j], 0.f);
          float h1 = fmaxf(t1 * qwa[j] + qba[j], 0.f);
          af[kc][j] = (_Float16)(h0 + h1);           // pads auto-zero
          float g0 = fmaxf(t0 * qwb[j] + qbb[j], 0.f);
          float g1 = fmaxf(t1 * qwb[j] + qbb[j], 0.f);
          af[kc][j + 4] = (_Float16)(g0 + g1);
        }
      }
      DO_MT(mt, af, 255);
    }
  }
  __syncthreads();

  // ---- level 7: 8 m-tiles, 2 per wave; preload-then-barrier for WAR ----
  {
    h8 a0[KC], a1[KC];
    LOAD_AFR(wave, a0);
    LOAD_AFR(wave + 4, a1);
    __syncthreads();
    DO_MT(wave, a0, 127);
    DO_MT(wave + 4, a1, 127);
  }
  __syncthreads();
  // ---- level 6: 4 m-tiles ----
  {
    h8 a0[KC];
    LOAD_AFR(wave, a0);
    __syncthreads();
    DO_MT(wave, a0, 63);
  }
  __syncthreads();
  // ---- level 5: 2 m-tiles ----
  {
    h8 a0[KC];
    if (wave < 2) LOAD_AFR(wave, a0);
    __syncthreads();
    if (wave < 2) DO_MT(wave, a0, 31);
  }
  __syncthreads();
  // ---- levels 4..0: single m-tile, wave 0 only (in-wave program order) ----
  if (wave == 0) {
    for (int d = 4; d >= 0; --d) {
      h8 a0[KC];
      LOAD_AFR(0, a0);
      DO_MT(0, a0, (1 << d) - 1);
    }
  }
  __syncthreads();

  // ---- projection: out[p] = root . Pw[p] + Pb[p], p<5 ----
  if (tid < 160) {
    const int p = tid >> 5;
    const int j = tid & 31;
    float sum = 0.f;
    #pragma unroll
    for (int c = 0; c < 4; ++c) {
      const int o = j + 32 * c;
      if (o < 100) sum += (float)Hs[0][o] * Pw[p * 100 + o];
    }
    sum += __shfl_down(sum, 16, 32);
    sum += __shfl_down(sum, 8, 32);
    sum += __shfl_down(sum, 4, 32);
    sum += __shfl_down(sum, 2, 32);
    sum += __shfl_down(sum, 1, 32);
    if (j == 0) out[tree * 5 + p] = sum + Pb[p];
  }
#undef DO_MT
#undef LOAD_AFR
}

extern "C" void kernel_launch(void* const* d_in, const int* in_sizes, int n_in,
                              void* d_out, int out_size, void* d_ws, size_t ws_size,
                              hipStream_t stream) {
  (void)n_in; (void)out_size; (void)d_ws; (void)ws_size;
  const float* times = (const float*)d_in[0];
  const float* Qw = (const float*)d_in[1];
  const float* Qb = (const float*)d_in[2];
  const float* Ww = (const float*)d_in[3];
  const float* Wb = (const float*)d_in[4];
  const float* Pw = (const float*)d_in[5];
  const float* Pb = (const float*)d_in[6];
  float* outp = (float*)d_out;
  const int B = in_sizes[0] / 1023;   // 1024 trees
  grnn_fused<<<dim3(B), dim3(256), 0, stream>>>(times, Qw, Qb, Ww, Wb, Pw, Pb, outp);
}

// Round 4
// 105.276 us; speedup vs baseline: 1.0625x; 1.0625x over previous
//
#include <hip/hip_runtime.h>

typedef _Float16 h8 __attribute__((ext_vector_type(8)));
typedef _Float16 h4 __attribute__((ext_vector_type(4)));
typedef float f4 __attribute__((ext_vector_type(4)));
typedef unsigned int uint32;

#define NT 7        // n-tiles: 112 output cols (100 + pad)
#define KC 4        // k-chunks of 32: k=0..99 real, k=100 -> t, k=101 -> 1
#define HSTRIDE 108 // elements/row; 54 words: bank=(22*l15+4*kg)%32 -> <=4-way

__global__ __launch_bounds__(256, 2)
void grnn_fused(const float* __restrict__ times,
                const float* __restrict__ Qw,
                const float* __restrict__ Qb,
                const float* __restrict__ Ww,
                const float* __restrict__ Wb,
                const float* __restrict__ Pw,
                const float* __restrict__ Pb,
                float* __restrict__ out)
{
  __shared__ __align__(16) _Float16 Hs[256][HSTRIDE]; // 55296 B; cols >=100 never read
  __shared__ __align__(8)  _Float16 ts[1026];         // f16 times at +1 offset
  __shared__ __align__(16) float qw_s[128];           // zero-padded
  __shared__ __align__(16) float qb_s[128];

  const int tid  = threadIdx.x;
  const int wave = tid >> 6;
  const int lane = tid & 63;
  const int l15  = lane & 15;
  const int kg   = lane >> 4;
  const int tree = blockIdx.x;

  // ---- phase 0: stage times (f16) and Q vectors ----
  {
    const float* tg = times + tree * 1023;
    for (int i = tid; i < 1023; i += 256) ts[1 + i] = (_Float16)tg[i];
    if (tid == 0) ts[0] = (_Float16)0.f;
    if (tid < 128) {
      float qw = 0.f, qb = 0.f;
      if (tid < 100) { qw = Qw[tid]; qb = Qb[tid]; }
      qw_s[tid] = qw; qb_s[tid] = qb;
    }
  }

  // ---- persistent W fragments straight from global (B[k][n] = Ww[n][k]);
  //      fold rows: B[100][n] = Qw[n], B[101][n] = Qb[n] + Wb[n] ----
  h8 wf[NT][KC];
  #pragma unroll
  for (int nt = 0; nt < NT; ++nt) {
    const int r = nt * 16 + l15;           // output feature (Ww row)
    #pragma unroll
    for (int kc = 0; kc < KC; ++kc) {
      h8 v;
      #pragma unroll
      for (int j = 0; j < 8; ++j) v[j] = (_Float16)0.f;
      if (r < 100) {
        const int kb = kc * 32 + kg * 8;
        if (kc < 3) {
          const f4 w0 = *(const f4*)&Ww[r * 100 + kb];
          const f4 w1 = *(const f4*)&Ww[r * 100 + kb + 4];
          #pragma unroll
          for (int j = 0; j < 4; ++j) {
            v[j]     = (_Float16)w0[j];
            v[j + 4] = (_Float16)w1[j];
          }
        } else if (kg == 0) {              // k = 96..103
          const f4 w0 = *(const f4*)&Ww[r * 100 + 96];
          #pragma unroll
          for (int j = 0; j < 4; ++j) v[j] = (_Float16)w0[j];
          v[4] = (_Float16)Qw[r];          // k=100
          v[5] = (_Float16)(Qb[r] + Wb[r]);// k=101
        }
      }
      wf[nt][kc] = v;
    }
  }
  __syncthreads();

// MFMA + ReLU-store epilogue. D row=(lane>>4)*4+reg, col=lane&15.
#define DO_MT(MT) do {                                                        \
    _Pragma("unroll")                                                         \
    for (int nt_ = 0; nt_ < NT; ++nt_) {                                      \
      f4 acc_ = {0.f, 0.f, 0.f, 0.f};                                         \
      _Pragma("unroll")                                                       \
      for (int kc_ = 0; kc_ < KC; ++kc_)                                      \
        acc_ = __builtin_amdgcn_mfma_f32_16x16x32_f16(af[kc_], wf[nt_][kc_],  \
                                                      acc_, 0, 0, 0);         \
      const int o_ = nt_ * 16 + l15;                                          \
      if (o_ < 100) {                                                         \
        const int mr_ = (MT) * 16 + kg * 4;                                   \
        _Pragma("unroll")                                                     \
        for (int r_ = 0; r_ < 4; ++r_)                                        \
          Hs[mr_ + r_][o_] = (_Float16)fmaxf(acc_[r_], 0.f);                  \
      }                                                                       \
    }                                                                         \
  } while (0)

// A[m=l15][k]: k<100 -> Hs[2m][k]+Hs[2m+1][k]; k=100 -> t(parent); k=101 -> 1
#define LOAD_AFR(MT, S) do {                                                  \
    const int m2_ = ((MT) * 16 + l15) * 2;                                    \
    _Pragma("unroll")                                                         \
    for (int kc_ = 0; kc_ < 3; ++kc_) {                                       \
      const int kb_ = kc_ * 32 + kg * 8;                                      \
      h4 a0_ = *(const h4*)&Hs[m2_][kb_];                                     \
      h4 b0_ = *(const h4*)&Hs[m2_][kb_ + 4];                                 \
      h4 a1_ = *(const h4*)&Hs[m2_ + 1][kb_];                                 \
      h4 b1_ = *(const h4*)&Hs[m2_ + 1][kb_ + 4];                             \
      h4 lo_ = a0_ + a1_, hi_ = b0_ + b1_;                                    \
      af[kc_] = __builtin_shufflevector(lo_, hi_, 0, 1, 2, 3, 4, 5, 6, 7);    \
    }                                                                         \
    if (kg == 0) {                                                            \
      h4 a0_ = *(const h4*)&Hs[m2_][96];                                      \
      h4 a1_ = *(const h4*)&Hs[m2_ + 1][96];                                  \
      h4 lo_ = a0_ + a1_;                                                     \
      h4 hi_ = {ts[1 + (S) + (MT) * 16 + l15], (_Float16)1.f,                 \
                (_Float16)0.f, (_Float16)0.f};                                \
      af[3] = __builtin_shufflevector(lo_, hi_, 0, 1, 2, 3, 4, 5, 6, 7);      \
    } else {                                                                  \
      _Pragma("unroll")                                                       \
      for (int j_ = 0; j_ < 8; ++j_) af[3][j_] = (_Float16)0.f;               \
    }                                                                         \
  } while (0)

  // ---- level 8 (256 nodes): leaves fused in VALU; no Hs reads -> no
  //      intra-level barriers. 16 m-tiles, 4 per wave, runtime loop. ----
  #pragma unroll 1
  for (int i = 0; i < 4; ++i) {
    const int mt = wave + 4 * i;
    const int m  = mt * 16 + l15;
    const uint32 tp = *(const uint32*)&ts[512 + 2 * m]; // leaf pair (aligned)
    const float t0 = (float)*(const _Float16*)&tp;
    const float t1 = (float)*((const _Float16*)&tp + 1);
    h8 af[KC];
    #pragma unroll
    for (int kc = 0; kc < KC; ++kc) {
      const int kb = kc * 32 + kg * 8;
      const f4 qwa = *(const f4*)&qw_s[kb];
      const f4 qwb = *(const f4*)&qw_s[kb + 4];
      const f4 qba = *(const f4*)&qb_s[kb];
      const f4 qbb = *(const f4*)&qb_s[kb + 4];
      #pragma unroll
      for (int j = 0; j < 4; ++j) {
        float h0 = fmaxf(t0 * qwa[j] + qba[j], 0.f);
        float h1 = fmaxf(t1 * qwa[j] + qba[j], 0.f);
        af[kc][j] = (_Float16)(h0 + h1);
        float g0 = fmaxf(t0 * qwb[j] + qbb[j], 0.f);
        float g1 = fmaxf(t1 * qwb[j] + qbb[j], 0.f);
        af[kc][j + 4] = (_Float16)(g0 + g1);
      }
    }
    if (kg == 0) {                       // fold slots k=100,101
      af[3][4] = ts[1 + 255 + m];
      af[3][5] = (_Float16)1.f;
      af[3][6] = (_Float16)0.f;
      af[3][7] = (_Float16)0.f;
    }
    DO_MT(mt);
  }

  // ---- levels 7..0: unified runtime loop, preload-then-barrier for WAR ----
  #pragma unroll 1
  for (int d = 7; d >= 0; --d) {
    const int s  = (1 << d) - 1;
    const int nm = (d >= 4) ? (1 << (d - 4)) : 1;   // m-tiles this level
    const bool mine = wave < (nm < 4 ? nm : 4);
    h8 af[KC];
    if (mine) LOAD_AFR(wave, s);
    __syncthreads();
    if (mine) {
      DO_MT(wave);
      if (nm == 8) {       // 2nd tile: children rows >=128, untouched this level
        LOAD_AFR(wave + 4, s);
        DO_MT(wave + 4);
      }
    }
    __syncthreads();
  }

  // ---- projection: out[p] = root . Pw[p] + Pb[p], p<5 ----
  if (tid < 160) {
    const int p = tid >> 5;
    const int j = tid & 31;
    float sum = 0.f;
    #pragma unroll
    for (int c = 0; c < 4; ++c) {
      const int o = j + 32 * c;
      if (o < 100) sum += (float)Hs[0][o] * Pw[p * 100 + o];
    }
    sum += __shfl_down(sum, 16, 32);
    sum += __shfl_down(sum, 8, 32);
    sum += __shfl_down(sum, 4, 32);
    sum += __shfl_down(sum, 2, 32);
    sum += __shfl_down(sum, 1, 32);
    if (j == 0) out[tree * 5 + p] = sum + Pb[p];
  }
#undef DO_MT
#undef LOAD_AFR
}

extern "C" void kernel_launch(void* const* d_in, const int* in_sizes, int n_in,
                              void* d_out, int out_size, void* d_ws, size_t ws_size,
                              hipStream_t stream) {
  (void)n_in; (void)out_size; (void)d_ws; (void)ws_size;
  const float* times = (const float*)d_in[0];
  const float* Qw = (const float*)d_in[1];
  const float* Qb = (const float*)d_in[2];
  const float* Ww = (const float*)d_in[3];
  const float* Wb = (const float*)d_in[4];
  const float* Pw = (const float*)d_in[5];
  const float* Pb = (const float*)d_in[6];
  float* outp = (float*)d_out;
  const int B = in_sizes[0] / 1023;   // 1024 trees
  grnn_fused<<<dim3(B), dim3(256), 0, stream>>>(times, Qw, Qb, Ww, Wb, Pw, Pb, outp);
}

// Round 6
// 101.464 us; speedup vs baseline: 1.1024x; 1.0376x over previous
//
#include <hip/hip_runtime.h>

typedef _Float16 h8 __attribute__((ext_vector_type(8)));
typedef _Float16 h4 __attribute__((ext_vector_type(4)));
typedef float f4 __attribute__((ext_vector_type(4)));
typedef unsigned int uint32;

#define NT 7        // n-tiles: 112 output features (100 + pad, pad never stored)
#define KC 4        // k-chunks of 32: k=0..99 real, k=100 -> t, k=101 -> 1
#define HSTRIDE 108 // word-stride/node-row = 54; 2-row step = 12 mod 32 -> <=4-way

__global__ __launch_bounds__(256, 2)
void grnn_fused(const float* __restrict__ times,
                const float* __restrict__ Qw,
                const float* __restrict__ Qb,
                const float* __restrict__ Ww,
                const float* __restrict__ Wb,
                const float* __restrict__ Pw,
                const float* __restrict__ Pb,
                float* __restrict__ out)
{
  __shared__ __align__(16) _Float16 Hs[256][HSTRIDE]; // 55296 B; cols >=100 never written/read
  __shared__ __align__(8)  _Float16 ts[1026];         // f16 times at +1 offset
  __shared__ __align__(16) float qw_s[128];           // zero-padded
  __shared__ __align__(16) float qb_s[128];

  const int tid  = threadIdx.x;
  const int wave = tid >> 6;
  const int lane = tid & 63;
  const int l15  = lane & 15;
  const int kg   = lane >> 4;
  const int tree = blockIdx.x;

  // ---- phase 0: stage times (f16) and Q vectors ----
  {
    const float* tg = times + tree * 1023;
    for (int i = tid; i < 1023; i += 256) ts[1 + i] = (_Float16)tg[i];
    if (tid == 0) ts[0] = (_Float16)0.f;
    if (tid < 128) {
      float qw = 0.f, qb = 0.f;
      if (tid < 100) { qw = Qw[tid]; qb = Qb[tid]; }
      qw_s[tid] = qw; qb_s[tid] = qb;
    }
  }

  // ---- persistent W fragments straight from global (B[k][n] = Ww[n][k]);
  //      fold rows: B[100][n] = Qw[n], B[101][n] = Qb[n] + Wb[n].
  //      A/B register layouts are symmetric -> same regs serve as A operand. ----
  h8 wf[NT][KC];
  #pragma unroll
  for (int nt = 0; nt < NT; ++nt) {
    const int r = nt * 16 + l15;           // output feature (Ww row)
    #pragma unroll
    for (int kc = 0; kc < KC; ++kc) {
      h8 v;
      #pragma unroll
      for (int j = 0; j < 8; ++j) v[j] = (_Float16)0.f;
      if (r < 100) {
        const int kb = kc * 32 + kg * 8;
        if (kc < 3) {
          const f4 w0 = *(const f4*)&Ww[r * 100 + kb];
          const f4 w1 = *(const f4*)&Ww[r * 100 + kb + 4];
          #pragma unroll
          for (int j = 0; j < 4; ++j) {
            v[j]     = (_Float16)w0[j];
            v[j + 4] = (_Float16)w1[j];
          }
        } else if (kg == 0) {              // k = 96..103
          const f4 w0 = *(const f4*)&Ww[r * 100 + 96];
          #pragma unroll
          for (int j = 0; j < 4; ++j) v[j] = (_Float16)w0[j];
          v[4] = (_Float16)Qw[r];          // k=100
          v[5] = (_Float16)(Qb[r] + Wb[r]);// k=101
        }
      }
      wf[nt][kc] = v;
    }
  }
  __syncthreads();

// Swapped-operand MFMA: D[m=feature][n=node]. Lane(l15,kg) reg r holds
// feature nt*16+kg*4+r of node MT*16+l15 -> one ds_write_b64 per nt.
// nt==6: only kg==0 (features 96..99) is real -> guard keeps stores in-row
// (unguarded kg=3 would hit cols 108..111 = next row's cols 0..3!).
#define DO_MT(MT) do {                                                        \
    _Pragma("unroll")                                                         \
    for (int nt_ = 0; nt_ < NT; ++nt_) {                                      \
      f4 acc_ = {0.f, 0.f, 0.f, 0.f};                                         \
      _Pragma("unroll")                                                       \
      for (int kc_ = 0; kc_ < KC; ++kc_)                                      \
        acc_ = __builtin_amdgcn_mfma_f32_16x16x32_f16(wf[nt_][kc_], af[kc_],  \
                                                      acc_, 0, 0, 0);         \
      if (nt_ < 6 || kg == 0) {                                               \
        h4 hv_ = {(_Float16)fmaxf(acc_[0], 0.f),                              \
                  (_Float16)fmaxf(acc_[1], 0.f),                              \
                  (_Float16)fmaxf(acc_[2], 0.f),                              \
                  (_Float16)fmaxf(acc_[3], 0.f)};                             \
        *(h4*)&Hs[(MT) * 16 + l15][nt_ * 16 + kg * 4] = hv_;                  \
      }                                                                       \
    }                                                                         \
  } while (0)

// af[m=node l15][k]: k<100 -> Hs[2m][k]+Hs[2m+1][k]; k=100 -> t; k=101 -> 1.
// Serves as B-operand B[k][n=node] under the swap (layout symmetry).
#define LOAD_AFR(MT, S) do {                                                  \
    const int m2_ = ((MT) * 16 + l15) * 2;                                    \
    _Pragma("unroll")                                                         \
    for (int kc_ = 0; kc_ < 3; ++kc_) {                                       \
      const int kb_ = kc_ * 32 + kg * 8;                                      \
      h4 a0_ = *(const h4*)&Hs[m2_][kb_];                                     \
      h4 b0_ = *(const h4*)&Hs[m2_][kb_ + 4];                                 \
      h4 a1_ = *(const h4*)&Hs[m2_ + 1][kb_];                                 \
      h4 b1_ = *(const h4*)&Hs[m2_ + 1][kb_ + 4];                             \
      h4 lo_ = a0_ + a1_, hi_ = b0_ + b1_;                                    \
      af[kc_] = __builtin_shufflevector(lo_, hi_, 0, 1, 2, 3, 4, 5, 6, 7);    \
    }                                                                         \
    if (kg == 0) {                                                            \
      h4 a0_ = *(const h4*)&Hs[m2_][96];                                      \
      h4 a1_ = *(const h4*)&Hs[m2_ + 1][96];                                  \
      h4 lo_ = a0_ + a1_;                                                     \
      h4 hi_ = {ts[1 + (S) + (MT) * 16 + l15], (_Float16)1.f,                 \
                (_Float16)0.f, (_Float16)0.f};                                \
      af[3] = __builtin_shufflevector(lo_, hi_, 0, 1, 2, 3, 4, 5, 6, 7);      \
    } else {                                                                  \
      _Pragma("unroll")                                                       \
      for (int j_ = 0; j_ < 8; ++j_) af[3][j_] = (_Float16)0.f;               \
    }                                                                         \
  } while (0)

  // ---- level 8 (256 nodes): leaves fused in VALU; 16 m-tiles, 4/wave ----
  #pragma unroll 1
  for (int i = 0; i < 4; ++i) {
    const int mt = wave + 4 * i;
    const int m  = mt * 16 + l15;
    const uint32 tp = *(const uint32*)&ts[512 + 2 * m]; // leaf pair (aligned)
    const float t0 = (float)*(const _Float16*)&tp;
    const float t1 = (float)*((const _Float16*)&tp + 1);
    h8 af[KC];
    #pragma unroll
    for (int kc = 0; kc < KC; ++kc) {
      const int kb = kc * 32 + kg * 8;
      const f4 qwa = *(const f4*)&qw_s[kb];
      const f4 qwb = *(const f4*)&qw_s[kb + 4];
      const f4 qba = *(const f4*)&qb_s[kb];
      const f4 qbb = *(const f4*)&qb_s[kb + 4];
      #pragma unroll
      for (int j = 0; j < 4; ++j) {
        float h0 = fmaxf(t0 * qwa[j] + qba[j], 0.f);
        float h1 = fmaxf(t1 * qwa[j] + qba[j], 0.f);
        af[kc][j] = (_Float16)(h0 + h1);
        float g0 = fmaxf(t0 * qwb[j] + qbb[j], 0.f);
        float g1 = fmaxf(t1 * qwb[j] + qbb[j], 0.f);
        af[kc][j + 4] = (_Float16)(g0 + g1);
      }
    }
    if (kg == 0) {                       // fold slots k=100,101
      af[3][4] = ts[1 + 255 + m];
      af[3][5] = (_Float16)1.f;
      af[3][6] = (_Float16)0.f;
      af[3][7] = (_Float16)0.f;
    }
    DO_MT(mt);
  }

  // ---- levels 7..0: runtime loop, preload-then-barrier for WAR ----
  #pragma unroll 1
  for (int d = 7; d >= 0; --d) {
    const int s  = (1 << d) - 1;
    const int nm = (d >= 4) ? (1 << (d - 4)) : 1;   // m-tiles this level
    const bool mine = wave < (nm < 4 ? nm : 4);
    h8 af[KC];
    if (mine) LOAD_AFR(wave, s);
    __syncthreads();
    if (mine) {
      DO_MT(wave);
      if (nm == 8) {       // 2nd tile: children rows >=128, untouched this level
        LOAD_AFR(wave + 4, s);
        DO_MT(wave + 4);
      }
    }
    __syncthreads();
  }

  // ---- projection: out[p] = root . Pw[p] + Pb[p], p<5 ----
  if (tid < 160) {
    const int p = tid >> 5;
    const int j = tid & 31;
    float sum = 0.f;
    #pragma unroll
    for (int c = 0; c < 4; ++c) {
      const int o = j + 32 * c;
      if (o < 100) sum += (float)Hs[0][o] * Pw[p * 100 + o];
    }
    sum += __shfl_down(sum, 16, 32);
    sum += __shfl_down(sum, 8, 32);
    sum += __shfl_down(sum, 4, 32);
    sum += __shfl_down(sum, 2, 32);
    sum += __shfl_down(sum, 1, 32);
    if (j == 0) out[tree * 5 + p] = sum + Pb[p];
  }
#undef DO_MT
#undef LOAD_AFR
}

extern "C" void kernel_launch(void* const* d_in, const int* in_sizes, int n_in,
                              void* d_out, int out_size, void* d_ws, size_t ws_size,
                              hipStream_t stream) {
  (void)n_in; (void)out_size; (void)d_ws; (void)ws_size;
  const float* times = (const float*)d_in[0];
  const float* Qw = (const float*)d_in[1];
  const float* Qb = (const float*)d_in[2];
  const float* Ww = (const float*)d_in[3];
  const float* Wb = (const float*)d_in[4];
  const float* Pw = (const float*)d_in[5];
  const float* Pb = (const float*)d_in[6];
  float* outp = (float*)d_out;
  const int B = in_sizes[0] / 1023;   // 1024 trees
  grnn_fused<<<dim3(B), dim3(256), 0, stream>>>(times, Qw, Qb, Ww, Wb, Pw, Pb, outp);
}